// Round 3
// baseline (540.913 us; speedup 1.0000x reference)
//
#include <hip/hip_runtime.h>
#include <hip/hip_bf16.h>

typedef __hip_bfloat16 bf16;

// Problem constants: b=32, C=128, H=W=64 -> n=4096, heads=4, dh=32, hidden=128.
// ALL inputs and the output are fp32 (reference dtypes; threshold arithmetic
// confirmed no bf16 floor). Intermediate q buffer kept bf16 for bandwidth.
//
// ws layout (float units):
//   S  [32][128][32]  @ 0        (131072)  token part of sum_n exp(k)*v   (atomics)
//   Z  [32][128]      @ 131072   (4096)    token part of sum_n exp(k)    (atomics)
//   Mt [32][128][128] @ 135168   (524288)  per-batch folded matrix, [hd][o]
//   Wt [128][384]     @ 659456   (49152)   w_qkv transposed
//   gs [128]          @ 708608   (128)     g * sqrt(C)
//   qb bf16 [32][128][4096] @ float offset 708736  (33.5 MB)

#define ROWP 65  // padded LDS row stride (floats) -> conflict-free row-varying reads

// ---------------- K0: init ----------------
__global__ void k0_init(const float* __restrict__ wqkv, const float* __restrict__ g,
                        float* __restrict__ ws) {
  int tid = blockIdx.x * blockDim.x + threadIdx.x;
  int stride = gridDim.x * blockDim.x;
  for (int i = tid; i < 135168; i += stride) ws[i] = 0.f;  // S + Z zeroed every call
  float* Wt = ws + 659456;
  for (int i = tid; i < 49152; i += stride) {
    int c = i / 384, o = i - c * 384;
    Wt[i] = wqkv[o * 128 + c];
  }
  float* gs = ws + 708608;
  if (tid < 128) gs[tid] = g[tid] * 11.313708498984761f;  // sqrt(128)
}

// ---------------- K1: rmsnorm + qkv + q-softmax + partial S,Z ----------------
// grid: 32 b * 64 tiles = 2048 blocks, 256 threads.
__global__ __launch_bounds__(256) void k1_qkv(
    const float* __restrict__ x, const float* __restrict__ Wt,
    const float* __restrict__ gs, float* __restrict__ S, float* __restrict__ Z,
    bf16* __restrict__ qb) {
  __shared__ float lds[2 * 128 * ROWP];  // kbuf | vbuf ; xn aliases kbuf region
  __shared__ float ssred[4 * 64];
  const int b = blockIdx.x >> 6;
  const int tile = blockIdx.x & 63;
  const int p0 = tile * 64;
  const int tid = threadIdx.x;
  const int p = tid & 63;
  const int w = tid >> 6;
  const int chunk = __builtin_amdgcn_readfirstlane(w);
  const int P = p0 + p;

  // phase 1: load x (coalesced: lane = pixel), per-pixel sum of squares
  const float* xb = x + (size_t)b * 128 * 4096 + P;
  float xr[32];
  float ss = 0.f;
#pragma unroll
  for (int i = 0; i < 32; i++) {
    int c = w + 4 * i;
    float v = xb[(size_t)c * 4096];
    xr[i] = v;
    ss += v * v;
  }
  ssred[w * 64 + p] = ss;
  __syncthreads();
  float tot = ssred[p] + ssred[64 + p] + ssred[128 + p] + ssred[192 + p];
  float inv = 1.0f / fmaxf(sqrtf(tot), 1e-12f);
  float* xn = lds;  // [c][ROWP]
#pragma unroll
  for (int i = 0; i < 32; i++) {
    int c = w + 4 * i;
    xn[c * ROWP + p] = xr[i] * gs[c] * inv;
  }
  __syncthreads();

  // phase 2: qkv GEMM. thread -> 96 outputs (o = chunk*96 + j), pixel p.
  // Wt index is wave-uniform -> scalar loads; xn from LDS (2-way = free).
  float acc[96];
#pragma unroll
  for (int j = 0; j < 96; j++) acc[j] = 0.f;
  const float* Wrow = Wt + chunk * 96;
  for (int c = 0; c < 128; c++) {
    float xv = xn[c * ROWP + p];
    const float* wr = Wrow + c * 384;
#pragma unroll
    for (int j = 0; j < 96; j++) acc[j] += wr[j] * xv;
  }
  __syncthreads();  // all xn reads done before kbuf/vbuf alias writes

  float* kbuf = lds;              // [h*32+d][ROWP] = exp(k)
  float* vbuf = lds + 128 * ROWP; // [h*32+e][ROWP] = v
#pragma unroll
  for (int s = 0; s < 3; s++) {
    int o0 = chunk * 96 + 32 * s;  // wave-uniform; aligned to head blocks of 32
    float* vals = acc + 32 * s;
    if (o0 < 128) {  // q head: softmax over d, *scale, store bf16
      int h = o0 >> 5;
      float m = vals[0];
#pragma unroll
      for (int d = 1; d < 32; d++) m = fmaxf(m, vals[d]);
      float sum = 0.f;
#pragma unroll
      for (int d = 0; d < 32; d++) {
        vals[d] = __expf(vals[d] - m);
        sum += vals[d];
      }
      float r = 0.17677669529663687f / sum;  // dh^-0.5 / sum
      bf16* qo = qb + (size_t)(b * 128 + h * 32) * 4096 + P;
#pragma unroll
      for (int d = 0; d < 32; d++) qo[(size_t)d * 4096] = __float2bfloat16(vals[d] * r);
    } else if (o0 < 256) {  // k head: exp (no max sub: |logit| small)
      int h = (o0 - 128) >> 5;
#pragma unroll
      for (int d = 0; d < 32; d++) kbuf[(h * 32 + d) * ROWP + p] = __expf(vals[d]);
    } else {  // v head
      int h = (o0 - 256) >> 5;
#pragma unroll
      for (int d = 0; d < 32; d++) vbuf[(h * 32 + d) * ROWP + p] = vals[d];
    }
  }
  __syncthreads();

  // phase 3: partial S[h][d][e] = sum_p expk*v, Z[h][d] = sum_p expk.
  // wave w == head; lane: d-pair {d0,d0+16}, e-octet [8*eq, 8*eq+8).
  const int h = chunk;
  const int l = tid & 63;
  const int d0 = l & 15;
  const int eq = l >> 4;
  float sacc0[8], sacc1[8];
#pragma unroll
  for (int j = 0; j < 8; j++) { sacc0[j] = 0.f; sacc1[j] = 0.f; }
  float z0 = 0.f, z1 = 0.f;
  const float* krow0 = kbuf + (h * 32 + d0) * ROWP;
  const float* krow1 = krow0 + 16 * ROWP;
  const float* vrow = vbuf + (h * 32 + 8 * eq) * ROWP;
#pragma unroll 4
  for (int pp = 0; pp < 64; pp++) {
    float k0v = krow0[pp], k1v = krow1[pp];
    z0 += k0v;
    z1 += k1v;
#pragma unroll
    for (int j = 0; j < 8; j++) {
      float vv = vrow[j * ROWP + pp];
      sacc0[j] += k0v * vv;
      sacc1[j] += k1v * vv;
    }
  }
  float* Sb = S + (size_t)b * 4096;
#pragma unroll
  for (int j = 0; j < 8; j++) {
    atomicAdd(&Sb[(h * 32 + d0) * 32 + 8 * eq + j], sacc0[j]);
    atomicAdd(&Sb[(h * 32 + d0 + 16) * 32 + 8 * eq + j], sacc1[j]);
  }
  if (eq == 0) {
    atomicAdd(&Z[b * 128 + h * 32 + d0], z0);
    atomicAdd(&Z[b * 128 + h * 32 + d0 + 16], z1);
  }
}

// ---------------- K2: context normalize + fold w_out -> Mt ----------------
// grid: 32 b * 4 quarters = 128 blocks, 256 threads.
__global__ void k2_ctx(const float* __restrict__ S, const float* __restrict__ Z,
                       const float* __restrict__ memkv, const float* __restrict__ wout,
                       float* __restrict__ Mt) {
  __shared__ float C[4096];   // [hd][e]
  __shared__ float zinv[128];
  const int b = blockIdx.x >> 2;
  const int qr = blockIdx.x & 3;
  const int tid = threadIdx.x;
  if (tid < 128) {  // Z += mem slots; invert
    int h = tid >> 5, d = tid & 31;
    float zm = 0.f;
#pragma unroll
    for (int j = 0; j < 4; j++)
      zm += __expf(memkv[(h * 32 + d) * 4 + j]);
    zinv[tid] = 1.0f / (Z[b * 128 + tid] + zm);
  }
  __syncthreads();
  for (int i = tid; i < 4096; i += 256) {  // C = (S + mem)/Ztot
    int hd = i >> 5, e = i & 31;
    int h = hd >> 5, d = hd & 31;
    float sm = 0.f;
#pragma unroll
    for (int j = 0; j < 4; j++) {
      float ek = __expf(memkv[(h * 32 + d) * 4 + j]);
      float mv = memkv[512 + (h * 32 + e) * 4 + j];  // mem_kv[1] starts at flat 512
      sm += ek * mv;
    }
    C[i] = (S[(size_t)b * 4096 + i] + sm) * zinv[hd];
  }
  __syncthreads();
  // Mt[hd][o] = sum_e wout[o][h*32+e] * C[hd][e], rows hd in this quarter
  for (int i = tid; i < 4096; i += 256) {
    int hd = qr * 32 + (i >> 7);
    int o = i & 127;
    int h = hd >> 5;
    float a = 0.f;
#pragma unroll
    for (int e = 0; e < 32; e++)
      a += wout[o * 128 + h * 32 + e] * C[hd * 32 + e];
    Mt[(size_t)b * 16384 + hd * 128 + o] = a;
  }
}

// ---------------- K3: out = Mt * q + b_out ----------------
// grid: 2048 blocks, 256 threads. Same scalar-weight GEMM structure as K1.
__global__ __launch_bounds__(256) void k3_out(
    const bf16* __restrict__ qb, const float* __restrict__ Mt,
    const float* __restrict__ bout, float* __restrict__ out) {
  __shared__ float qt[128 * ROWP];
  const int b = blockIdx.x >> 6;
  const int tile = blockIdx.x & 63;
  const int p0 = tile * 64;
  const int tid = threadIdx.x;
  const int p = tid & 63;
  const int w = tid >> 6;
  const int chunk = __builtin_amdgcn_readfirstlane(w);
  const int P = p0 + p;
  const bf16* qbb = qb + (size_t)b * 128 * 4096 + P;
#pragma unroll
  for (int i = 0; i < 32; i++) {
    int hd = w + 4 * i;
    qt[hd * ROWP + p] = __bfloat162float(qbb[(size_t)hd * 4096]);
  }
  __syncthreads();
  float acc[32];
#pragma unroll
  for (int j = 0; j < 32; j++) acc[j] = 0.f;
  const float* Mrow = Mt + (size_t)b * 16384 + chunk * 32;
  for (int hd = 0; hd < 128; hd++) {
    float qv = qt[hd * ROWP + p];
    const float* mr = Mrow + hd * 128;
#pragma unroll
    for (int j = 0; j < 32; j++) acc[j] += mr[j] * qv;
  }
  float* ob = out + (size_t)b * 128 * 4096 + P;
  const int o0 = chunk * 32;
#pragma unroll
  for (int j = 0; j < 32; j++) {
    ob[(size_t)(o0 + j) * 4096] = acc[j] + bout[o0 + j];
  }
}

extern "C" void kernel_launch(void* const* d_in, const int* in_sizes, int n_in,
                              void* d_out, int out_size, void* d_ws, size_t ws_size,
                              hipStream_t stream) {
  const float* x     = (const float*)d_in[0];
  const float* g     = (const float*)d_in[1];
  const float* wqkv  = (const float*)d_in[2];
  const float* memkv = (const float*)d_in[3];
  const float* wout  = (const float*)d_in[4];
  const float* bout  = (const float*)d_in[5];
  float* out = (float*)d_out;
  float* ws = (float*)d_ws;
  float* S  = ws;
  float* Zp = ws + 131072;
  float* Mt = ws + 135168;
  float* Wt = ws + 659456;
  float* gs = ws + 708608;
  bf16* qb  = (bf16*)(ws + 708736);

  k0_init<<<256, 256, 0, stream>>>(wqkv, g, ws);
  k1_qkv<<<2048, 256, 0, stream>>>(x, Wt, gs, S, Zp, qb);
  k2_ctx<<<128, 256, 0, stream>>>(S, Zp, memkv, wout, Mt);
  k3_out<<<2048, 256, 0, stream>>>(qb, Mt, bout, out);
}

// Round 4
// 400.404 us; speedup vs baseline: 1.3509x; 1.3509x over previous
//
#include <hip/hip_runtime.h>
#include <hip/hip_bf16.h>

typedef __attribute__((ext_vector_type(8))) short short8;   // 8 bf16 (A/B frag)
typedef __attribute__((ext_vector_type(4))) float f32x4;    // 4 fp32 (C/D frag)

// b=32, C=128, n=4096 (64 px/tile * 64 tiles), heads=4, dh=32.
// All I/O fp32. MFMA path: bf16 frags, fp32 accumulate.
//
// ws (float units):
//   S   [32][128][32]        @ 0       (131072)  fp32 atomics
//   Z   [32][128]            @ 131072  (4096)
//   Mtf bf16 frag-major      @ 135168  (262144 floats = 32*32 frags*512 bf16)
//   Wf  bf16 frag-major      @ 397312  (24576 floats = 96 frags*512 bf16)
//   gs  [128]                @ 421888  (128)
//   qbf bf16 frag-major      @ 422016  (8388608 floats = 32*64 tiles*16 frags*512)

__device__ __forceinline__ unsigned short f2bf(float f) {  // RNE, finite inputs
  unsigned u = __float_as_uint(f);
  u += 0x7fff + ((u >> 16) & 1);
  return (unsigned short)(u >> 16);
}

// ---------------- K0: zero S/Z, pack Wf frag-major, gs ----------------
__global__ void k0_init(const float* __restrict__ wqkv, const float* __restrict__ g,
                        float* __restrict__ ws) {
  int tid = blockIdx.x * blockDim.x + threadIdx.x;
  int stride = gridDim.x * blockDim.x;
  for (int i = tid; i < 135168; i += stride) ws[i] = 0.f;
  unsigned short* Wf = (unsigned short*)(ws + 397312);
  for (int i = tid; i < 49152; i += stride) {
    int o = i >> 7, c = i & 127;
    int f = (o >> 4) * 4 + (c >> 5);
    int lane = (o & 15) + (((c >> 3) & 3) << 4);
    Wf[f * 512 + lane * 8 + (c & 7)] = f2bf(wqkv[o * 128 + c]);
  }
  float* gs = ws + 421888;
  if (tid < 128) gs[tid] = g[tid] * 11.313708498984761f;  // sqrt(128)
}

// ---------------- K1: rmsnorm + MFMA qkv + q-softmax + partial S,Z ----------------
__global__ __launch_bounds__(256) void k1_qkv(
    const float* __restrict__ x, const unsigned short* __restrict__ Wf,
    const float* __restrict__ gs, float* __restrict__ S, float* __restrict__ Z,
    unsigned short* __restrict__ qbf) {
  __shared__ __align__(16) unsigned short xnf[16 * 512];   // B-frags of xn
  __shared__ unsigned short kbuf[128 * 66];                // exp(k) [row][px]
  __shared__ unsigned short vbuf[128 * 66];                // v      [row][px]
  __shared__ float ssred[256];
  const int b = blockIdx.x >> 6, tile = blockIdx.x & 63;
  const int tid = threadIdx.x;
  const int p = tid & 63, w = tid >> 6;
  const int chunk = __builtin_amdgcn_readfirstlane(w);
  const int l = p, quad = l >> 4, l16 = l & 15;
  const int P = tile * 64 + p;

  // phase 1: load x (c = w*32+i), rmsnorm, write B-frags
  const float* xb = x + (size_t)b * 524288 + P;
  float xr[32];
  float ss = 0.f;
#pragma unroll
  for (int i = 0; i < 32; i++) {
    float v = xb[(size_t)(w * 32 + i) * 4096];
    xr[i] = v; ss += v * v;
  }
  ssred[w * 64 + p] = ss;
  __syncthreads();
  float tot = ssred[p] + ssred[64 + p] + ssred[128 + p] + ssred[192 + p];
  float inv = 1.0f / fmaxf(sqrtf(tot), 1e-12f);
#pragma unroll
  for (int q8 = 0; q8 < 4; q8++) {
    short8 v8;
#pragma unroll
    for (int j = 0; j < 8; j++) {
      int i = q8 * 8 + j;
      v8[j] = (short)f2bf(xr[i] * gs[w * 32 + i] * inv);
    }
    // frag fb = k0*4+n0 with k0=w, n0=p>>4; lane' = (p&15)+q8*16
    *(short8*)&xnf[(w * 4 + (p >> 4)) * 512 + ((p & 15) + q8 * 16) * 8] = v8;
  }
  __syncthreads();

  // phase 2: MFMA. wave 'chunk' -> outputs [chunk*96, chunk*96+96)
  f32x4 acc[6][4] = {};
  const short8* Wfv = (const short8*)Wf;
#pragma unroll
  for (int k0 = 0; k0 < 4; k0++) {
    short8 bfr[4];
#pragma unroll
    for (int n0 = 0; n0 < 4; n0++)
      bfr[n0] = *(const short8*)&xnf[(k0 * 4 + n0) * 512 + l * 8];
#pragma unroll
    for (int m0 = 0; m0 < 6; m0++) {
      short8 afr = Wfv[((chunk * 6 + m0) * 4 + k0) * 64 + l];
#pragma unroll
      for (int n0 = 0; n0 < 4; n0++)
        acc[m0][n0] = __builtin_amdgcn_mfma_f32_16x16x32_bf16(afr, bfr[n0], acc[m0][n0], 0, 0, 0);
    }
  }
  __syncthreads();  // xnf reads done (kbuf/vbuf are separate, but sync orders phase 4 deps)

  // phase 3 epilogue: C/D element (m0,n0,reg) = QKV[chunk*96+m0*16+quad*4+reg][n0*16+l16]
#pragma unroll
  for (int s = 0; s < 3; s++) {
    int o0 = chunk * 96 + 32 * s;
    if (o0 < 128) {  // q head: per-pixel softmax over d (32 rows = 2 tiles)
      int h = o0 >> 5;
#pragma unroll
      for (int n0 = 0; n0 < 4; n0++) {
        float m = -1e30f;
#pragma unroll
        for (int off = 0; off < 2; off++)
#pragma unroll
          for (int r = 0; r < 4; r++) m = fmaxf(m, acc[2 * s + off][n0][r]);
        m = fmaxf(m, __shfl_xor(m, 16, 64));
        m = fmaxf(m, __shfl_xor(m, 32, 64));
        float e[2][4]; float sum = 0.f;
#pragma unroll
        for (int off = 0; off < 2; off++)
#pragma unroll
          for (int r = 0; r < 4; r++) {
            e[off][r] = __expf(acc[2 * s + off][n0][r] - m);
            sum += e[off][r];
          }
        sum += __shfl_xor(sum, 16, 64);
        sum += __shfl_xor(sum, 32, 64);
        float rs = 0.17677669529663687f / sum;  // dh^-0.5 / sum
        int base = ((b * 64 + tile) * 16 + h * 4 + n0) * 512;
#pragma unroll
        for (int off = 0; off < 2; off++)
#pragma unroll
          for (int r = 0; r < 4; r++) {
            // d = off*16+quad*4+r; store in K3 B-frag layout
            int lane2 = l16 + ((off * 2 + (quad >> 1)) << 4);
            int jj = (quad & 1) * 4 + r;
            qbf[base + lane2 * 8 + jj] = f2bf(e[off][r] * rs);
          }
      }
    } else if (o0 < 256) {  // k head rows r0..r0+31 -> exp -> LDS
      int r0 = o0 - 128;
#pragma unroll
      for (int n0 = 0; n0 < 4; n0++)
#pragma unroll
        for (int off = 0; off < 2; off++)
#pragma unroll
          for (int r = 0; r < 4; r++) {
            int row = r0 + off * 16 + quad * 4 + r;
            kbuf[row * 66 + n0 * 16 + l16] = f2bf(__expf(acc[2 * s + off][n0][r]));
          }
    } else {  // v head
      int r0 = o0 - 256;
#pragma unroll
      for (int n0 = 0; n0 < 4; n0++)
#pragma unroll
        for (int off = 0; off < 2; off++)
#pragma unroll
          for (int r = 0; r < 4; r++) {
            int row = r0 + off * 16 + quad * 4 + r;
            vbuf[row * 66 + n0 * 16 + l16] = f2bf(acc[2 * s + off][n0][r]);
          }
    }
  }
  __syncthreads();

  // phase 4: S[hd][e] += sum_p expk*v ; Z[hd] += sum_p expk. wave = head.
  const int h = chunk, d0 = l16, eq = quad;
  float sacc0[8], sacc1[8];
#pragma unroll
  for (int j = 0; j < 8; j++) { sacc0[j] = 0.f; sacc1[j] = 0.f; }
  float z0 = 0.f, z1 = 0.f;
  const unsigned short* kr0 = kbuf + (h * 32 + d0) * 66;
  const unsigned short* kr1 = kr0 + 16 * 66;
  const unsigned short* vr = vbuf + (h * 32 + 8 * eq) * 66;
#pragma unroll 4
  for (int pp = 0; pp < 32; pp++) {  // 2 pixels/iter (packed bf16 pair)
    unsigned ka = *(const unsigned*)&kr0[2 * pp];
    unsigned kc = *(const unsigned*)&kr1[2 * pp];
    float k0e = __uint_as_float(ka << 16), k0o = __uint_as_float(ka & 0xffff0000u);
    float k1e = __uint_as_float(kc << 16), k1o = __uint_as_float(kc & 0xffff0000u);
    z0 += k0e + k0o; z1 += k1e + k1o;
#pragma unroll
    for (int j = 0; j < 8; j++) {
      unsigned vv = *(const unsigned*)&vr[j * 66 + 2 * pp];
      float ve = __uint_as_float(vv << 16), vo = __uint_as_float(vv & 0xffff0000u);
      sacc0[j] += k0e * ve + k0o * vo;
      sacc1[j] += k1e * ve + k1o * vo;
    }
  }
  float* Sb = S + (size_t)b * 4096;
#pragma unroll
  for (int j = 0; j < 8; j++) {
    atomicAdd(&Sb[(h * 32 + d0) * 32 + 8 * eq + j], sacc0[j]);
    atomicAdd(&Sb[(h * 32 + d0 + 16) * 32 + 8 * eq + j], sacc1[j]);
  }
  if (eq == 0) {
    atomicAdd(&Z[b * 128 + h * 32 + d0], z0);
    atomicAdd(&Z[b * 128 + h * 32 + d0 + 16], z1);
  }
}

// ---------------- K2: context + fold w_out -> Mtf (bf16 frag-major) ----------------
__global__ void k2_ctx(const float* __restrict__ S, const float* __restrict__ Z,
                       const float* __restrict__ memkv, const float* __restrict__ wout,
                       unsigned short* __restrict__ Mtf) {
  __shared__ float C[4096];
  __shared__ float zinv[128];
  const int b = blockIdx.x >> 2, qr = blockIdx.x & 3, tid = threadIdx.x;
  if (tid < 128) {
    float zm = 0.f;
#pragma unroll
    for (int j = 0; j < 4; j++) zm += __expf(memkv[tid * 4 + j]);
    zinv[tid] = 1.0f / (Z[b * 128 + tid] + zm);
  }
  __syncthreads();
  for (int i = tid; i < 4096; i += 256) {
    int hd = i >> 5, e = i & 31, h = hd >> 5;
    float sm = 0.f;
#pragma unroll
    for (int j = 0; j < 4; j++)
      sm += __expf(memkv[hd * 4 + j]) * memkv[512 + (h * 32 + e) * 4 + j];
    C[i] = (S[(size_t)b * 4096 + i] + sm) * zinv[hd];
  }
  __syncthreads();
  for (int i = tid; i < 4096; i += 256) {
    int hd = qr * 32 + (i >> 7);
    int o = i & 127, h = hd >> 5;
    float a = 0.f;
#pragma unroll
    for (int e = 0; e < 32; e++) a += wout[o * 128 + h * 32 + e] * C[hd * 32 + e];
    int f = (o >> 4) * 4 + (hd >> 5);
    int lane = (o & 15) + (((hd >> 3) & 3) << 4);
    Mtf[(size_t)b * 16384 + f * 512 + lane * 8 + (hd & 7)] = f2bf(a);
  }
}

// ---------------- K3: out = Mtf x q + b_out (MFMA) ----------------
__global__ __launch_bounds__(256) void k3_out(
    const unsigned short* __restrict__ qbf, const unsigned short* __restrict__ Mtf,
    const float* __restrict__ bout, float* __restrict__ out) {
  __shared__ __align__(16) unsigned short qf[16 * 512];
  const int b = blockIdx.x >> 6, tile = blockIdx.x & 63;
  const int tid = threadIdx.x;
  const int l = tid & 63, quad = l >> 4, l16 = l & 15;
  const int chunk = __builtin_amdgcn_readfirstlane(tid >> 6);
  const short8* qv = (const short8*)qbf;
  const int base = ((b * 64 + tile) * 16) * 64;  // short8 units
#pragma unroll
  for (int r = 0; r < 4; r++) {
    int cid = tid + 256 * r;
    *(short8*)&qf[cid * 8] = qv[base + cid];
  }
  __syncthreads();
  f32x4 acc[2][4] = {};
  const short8* Mv = (const short8*)Mtf;
#pragma unroll
  for (int k0 = 0; k0 < 4; k0++) {
    short8 bfr[4];
#pragma unroll
    for (int n0 = 0; n0 < 4; n0++)
      bfr[n0] = *(const short8*)&qf[(k0 * 4 + n0) * 512 + l * 8];
#pragma unroll
    for (int mm = 0; mm < 2; mm++) {
      short8 afr = Mv[((size_t)b * 32 + (chunk * 2 + mm) * 4 + k0) * 64 + l];
#pragma unroll
      for (int n0 = 0; n0 < 4; n0++)
        acc[mm][n0] = __builtin_amdgcn_mfma_f32_16x16x32_bf16(afr, bfr[n0], acc[mm][n0], 0, 0, 0);
    }
  }
  float bv[2][4];
#pragma unroll
  for (int mm = 0; mm < 2; mm++)
#pragma unroll
    for (int r = 0; r < 4; r++) bv[mm][r] = bout[chunk * 32 + mm * 16 + quad * 4 + r];
#pragma unroll
  for (int mm = 0; mm < 2; mm++)
#pragma unroll
    for (int n0 = 0; n0 < 4; n0++)
#pragma unroll
      for (int r = 0; r < 4; r++) {
        int o = chunk * 32 + mm * 16 + quad * 4 + r;
        int Pp = tile * 64 + n0 * 16 + l16;
        out[((size_t)b * 128 + o) * 4096 + Pp] = acc[mm][n0][r] + bv[mm][r];
      }
}

extern "C" void kernel_launch(void* const* d_in, const int* in_sizes, int n_in,
                              void* d_out, int out_size, void* d_ws, size_t ws_size,
                              hipStream_t stream) {
  const float* x     = (const float*)d_in[0];
  const float* g     = (const float*)d_in[1];
  const float* wqkv  = (const float*)d_in[2];
  const float* memkv = (const float*)d_in[3];
  const float* wout  = (const float*)d_in[4];
  const float* bout  = (const float*)d_in[5];
  float* out = (float*)d_out;
  float* ws = (float*)d_ws;
  float* S   = ws;
  float* Zp  = ws + 131072;
  unsigned short* Mtf = (unsigned short*)(ws + 135168);
  unsigned short* Wf  = (unsigned short*)(ws + 397312);
  float* gs  = ws + 421888;
  unsigned short* qbf = (unsigned short*)(ws + 422016);

  k0_init<<<128, 256, 0, stream>>>(wqkv, g, ws);
  k1_qkv<<<2048, 256, 0, stream>>>(x, Wf, gs, S, Zp, qbf);
  k2_ctx<<<128, 256, 0, stream>>>(S, Zp, memkv, wout, Mtf);
  k3_out<<<2048, 256, 0, stream>>>(qbf, Mtf, bout, out);
}

// Round 5
// 232.189 us; speedup vs baseline: 2.3296x; 1.7245x over previous
//
#include <hip/hip_runtime.h>
#include <hip/hip_bf16.h>

typedef __attribute__((ext_vector_type(8))) short short8;   // 8 bf16 (A/B frag)
typedef __attribute__((ext_vector_type(4))) float f32x4;    // 4 fp32 (C/D frag)

// b=32, C=128, n=4096, heads=4, dh=32. All I/O fp32; MFMA bf16, fp32 accum.
// NO global atomics: K1 writes per-block S/Z partials, K2 reduces them.
//
// ws (float units):
//   Sp  [32][16][4096] @ 0        (2097152)  per-block-group S partials
//   Zp  [32][16][128]  @ 2097152  (65536)
//   Mtf bf16 frag-major @ 2162688 (262144 fl = 32*32 frags*512 bf16)
//   Wf  bf16 frag-major @ 2424832 (24576 fl = 96 frags*512 bf16)
//   gs  [128]           @ 2449408 (128)
//   qbf bf16 frag-major @ 2449536 (8388608 fl = 32*64*16 frags*512 bf16)
//   end 10838144 floats = 43.4 MB

__device__ __forceinline__ unsigned short f2bf(float f) {  // RNE, finite inputs
  unsigned u = __float_as_uint(f);
  u += 0x7fff + ((u >> 16) & 1);
  return (unsigned short)(u >> 16);
}

// ---------------- K0: pack Wf frag-major, gs ----------------
__global__ void k0_init(const float* __restrict__ wqkv, const float* __restrict__ g,
                        float* __restrict__ ws) {
  int tid = blockIdx.x * blockDim.x + threadIdx.x;
  int stride = gridDim.x * blockDim.x;
  unsigned short* Wf = (unsigned short*)(ws + 2424832);
  for (int i = tid; i < 49152; i += stride) {
    int o = i >> 7, c = i & 127;
    int f = (o >> 4) * 4 + (c >> 5);
    int lane = (o & 15) + (((c >> 3) & 3) << 4);
    Wf[f * 512 + lane * 8 + (c & 7)] = f2bf(wqkv[o * 128 + c]);
  }
  float* gs = ws + 2449408;
  if (tid < 128) gs[tid] = g[tid] * 11.313708498984761f;  // sqrt(128)
}

// ---------------- K1: rmsnorm + MFMA qkv + q-softmax + S/Z partials ----------------
// grid 512 = 32 b * 16 groups; each block does 4 sub-tiles of 64 px.
__global__ __launch_bounds__(256) void k1_qkv(
    const float* __restrict__ x, const unsigned short* __restrict__ Wf,
    const float* __restrict__ gs, float* __restrict__ Sp, float* __restrict__ Zp,
    unsigned short* __restrict__ qbf) {
  __shared__ __align__(16) unsigned short xnf[16 * 512];   // B-frags / q-stage
  __shared__ unsigned short kbuf[128 * 66];                // exp(k) [row][px]
  __shared__ unsigned short vbuf[128 * 66];                // v      [row][px]
  __shared__ float ssred[256];
  const int b = blockIdx.x >> 4, grp = blockIdx.x & 15;
  const int tid = threadIdx.x;
  const int p = tid & 63, w = tid >> 6;
  const int chunk = __builtin_amdgcn_readfirstlane(w);
  const int l = p, quad = l >> 4, l16 = l & 15;

  // phase-4 accumulators persist across sub-tiles
  const int h4 = chunk, d0 = l16, eq = quad;
  float sacc0[8] = {}, sacc1[8] = {};
  float z0 = 0.f, z1 = 0.f;

  for (int t = 0; t < 4; t++) {
    const int tile = grp * 4 + t;
    const int P = tile * 64 + p;
    // phase 1: load x (c = w*32+i), rmsnorm
    const float* xb = x + (size_t)b * 524288 + P;
    float xr[32];
    float ss = 0.f;
#pragma unroll
    for (int i = 0; i < 32; i++) {
      float v = xb[(size_t)(w * 32 + i) * 4096];
      xr[i] = v; ss += v * v;
    }
    ssred[w * 64 + p] = ss;
    __syncthreads();  // ssred ready; prev iter's LDS readers (phase4/qstore) done
    float tot = ssred[p] + ssred[64 + p] + ssred[128 + p] + ssred[192 + p];
    float inv = 1.0f / fmaxf(sqrtf(tot), 1e-12f);
#pragma unroll
    for (int q8 = 0; q8 < 4; q8++) {
      short8 v8;
#pragma unroll
      for (int j = 0; j < 8; j++) {
        int i = q8 * 8 + j;
        v8[j] = (short)f2bf(xr[i] * gs[w * 32 + i] * inv);
      }
      *(short8*)&xnf[(w * 4 + (p >> 4)) * 512 + ((p & 15) + q8 * 16) * 8] = v8;
    }
    __syncthreads();  // xnf ready

    // phase 2: MFMA. wave 'chunk' -> outputs [chunk*96, chunk*96+96)
    f32x4 acc[6][4] = {};
    const short8* Wfv = (const short8*)Wf;
#pragma unroll
    for (int k0 = 0; k0 < 4; k0++) {
      short8 bfr[4];
#pragma unroll
      for (int n0 = 0; n0 < 4; n0++)
        bfr[n0] = *(const short8*)&xnf[(k0 * 4 + n0) * 512 + l * 8];
#pragma unroll
      for (int m0 = 0; m0 < 6; m0++) {
        short8 afr = Wfv[((chunk * 6 + m0) * 4 + k0) * 64 + l];
#pragma unroll
        for (int n0 = 0; n0 < 4; n0++)
          acc[m0][n0] = __builtin_amdgcn_mfma_f32_16x16x32_bf16(afr, bfr[n0], acc[m0][n0], 0, 0, 0);
      }
    }
    __syncthreads();  // xnf MFMA-reads done -> may overwrite as q-stage

    // phase 3 epilogue: C/D (m0,n0,reg) = QKV[chunk*96+m0*16+quad*4+reg][n0*16+l16]
#pragma unroll
    for (int s = 0; s < 3; s++) {
      int o0 = chunk * 96 + 32 * s;
      if (o0 < 128) {  // q head: per-pixel softmax over d
        int h = o0 >> 5;
#pragma unroll
        for (int n0 = 0; n0 < 4; n0++) {
          float m = -1e30f;
#pragma unroll
          for (int off = 0; off < 2; off++)
#pragma unroll
            for (int r = 0; r < 4; r++) m = fmaxf(m, acc[2 * s + off][n0][r]);
          m = fmaxf(m, __shfl_xor(m, 16, 64));
          m = fmaxf(m, __shfl_xor(m, 32, 64));
          float e[2][4]; float sum = 0.f;
#pragma unroll
          for (int off = 0; off < 2; off++)
#pragma unroll
            for (int r = 0; r < 4; r++) {
              e[off][r] = __expf(acc[2 * s + off][n0][r] - m);
              sum += e[off][r];
            }
          sum += __shfl_xor(sum, 16, 64);
          sum += __shfl_xor(sum, 32, 64);
          float rs = 0.17677669529663687f / sum;  // dh^-0.5 / sum
          int qbase = (h * 4 + n0) * 512;
#pragma unroll
          for (int off = 0; off < 2; off++)
#pragma unroll
            for (int r = 0; r < 4; r++) {
              int lane2 = l16 + ((off * 2 + (quad >> 1)) << 4);
              int jj = (quad & 1) * 4 + r;
              xnf[qbase + lane2 * 8 + jj] = f2bf(e[off][r] * rs);
            }
        }
      } else if (o0 < 256) {  // k head rows -> exp -> LDS
        int r0 = o0 - 128;
#pragma unroll
        for (int n0 = 0; n0 < 4; n0++)
#pragma unroll
          for (int off = 0; off < 2; off++)
#pragma unroll
            for (int r = 0; r < 4; r++) {
              int row = r0 + off * 16 + quad * 4 + r;
              kbuf[row * 66 + n0 * 16 + l16] = f2bf(__expf(acc[2 * s + off][n0][r]));
            }
      } else {  // v head
        int r0 = o0 - 256;
#pragma unroll
        for (int n0 = 0; n0 < 4; n0++)
#pragma unroll
          for (int off = 0; off < 2; off++)
#pragma unroll
            for (int r = 0; r < 4; r++) {
              int row = r0 + off * 16 + quad * 4 + r;
              vbuf[row * 66 + n0 * 16 + l16] = f2bf(acc[2 * s + off][n0][r]);
            }
      }
    }
    __syncthreads();

    // phase 4a: coalesced qbf store from LDS stage (16 frags * 512 bf16 = 1024 short8)
    {
      const short8* qs = (const short8*)xnf;
      short8* qg = ((short8*)qbf) + (size_t)(b * 64 + tile) * 16 * 64;
#pragma unroll
      for (int r = 0; r < 4; r++) qg[tid + 256 * r] = qs[tid + 256 * r];
    }
    // phase 4b: accumulate S/Z for this sub-tile. wave = head.
    const unsigned short* kr0 = kbuf + (h4 * 32 + d0) * 66;
    const unsigned short* kr1 = kr0 + 16 * 66;
    const unsigned short* vr = vbuf + (h4 * 32 + 8 * eq) * 66;
#pragma unroll 4
    for (int pp = 0; pp < 32; pp++) {  // 2 px/iter (packed bf16 pair)
      unsigned ka = *(const unsigned*)&kr0[2 * pp];
      unsigned kc = *(const unsigned*)&kr1[2 * pp];
      float k0e = __uint_as_float(ka << 16), k0o = __uint_as_float(ka & 0xffff0000u);
      float k1e = __uint_as_float(kc << 16), k1o = __uint_as_float(kc & 0xffff0000u);
      z0 += k0e + k0o; z1 += k1e + k1o;
#pragma unroll
      for (int j = 0; j < 8; j++) {
        unsigned vv = *(const unsigned*)&vr[j * 66 + 2 * pp];
        float ve = __uint_as_float(vv << 16), vo = __uint_as_float(vv & 0xffff0000u);
        sacc0[j] += k0e * ve + k0o * vo;
        sacc1[j] += k1e * ve + k1o * vo;
      }
    }
  }

  // write partials (coalesced float4, no atomics)
  float* Spb = Sp + (size_t)(b * 16 + grp) * 4096;
  f32x4 s0a = {sacc0[0], sacc0[1], sacc0[2], sacc0[3]};
  f32x4 s0b = {sacc0[4], sacc0[5], sacc0[6], sacc0[7]};
  f32x4 s1a = {sacc1[0], sacc1[1], sacc1[2], sacc1[3]};
  f32x4 s1b = {sacc1[4], sacc1[5], sacc1[6], sacc1[7]};
  *(f32x4*)&Spb[(h4 * 32 + d0) * 32 + 8 * eq] = s0a;
  *(f32x4*)&Spb[(h4 * 32 + d0) * 32 + 8 * eq + 4] = s0b;
  *(f32x4*)&Spb[(h4 * 32 + d0 + 16) * 32 + 8 * eq] = s1a;
  *(f32x4*)&Spb[(h4 * 32 + d0 + 16) * 32 + 8 * eq + 4] = s1b;
  if (eq == 0) {
    Zp[(b * 16 + grp) * 128 + h4 * 32 + d0] = z0;
    Zp[(b * 16 + grp) * 128 + h4 * 32 + d0 + 16] = z1;
  }
}

// ---------------- K2: reduce partials + context + fold w_out -> Mtf ----------------
__global__ void k2_ctx(const float* __restrict__ Sp, const float* __restrict__ Zp,
                       const float* __restrict__ memkv, const float* __restrict__ wout,
                       unsigned short* __restrict__ Mtf) {
  __shared__ float C[1024];    // this quarter's rows [32][32]
  __shared__ float zinv[128];
  const int b = blockIdx.x >> 2, qr = blockIdx.x & 3, tid = threadIdx.x;
  if (tid < 128) {
    float z = 0.f;
#pragma unroll
    for (int g = 0; g < 16; g++) z += Zp[(b * 16 + g) * 128 + tid];
    float zm = 0.f;
#pragma unroll
    for (int j = 0; j < 4; j++) zm += __expf(memkv[tid * 4 + j]);
    zinv[tid] = 1.0f / (z + zm);
  }
  __syncthreads();
  for (int i = tid; i < 1024; i += 256) {
    int idx = qr * 1024 + i;
    int hd = idx >> 5, e = idx & 31, h = hd >> 5;
    float s = 0.f;
#pragma unroll
    for (int g = 0; g < 16; g++) s += Sp[(size_t)(b * 16 + g) * 4096 + idx];
    float sm = 0.f;
#pragma unroll
    for (int j = 0; j < 4; j++)
      sm += __expf(memkv[hd * 4 + j]) * memkv[512 + (h * 32 + e) * 4 + j];
    C[i] = (s + sm) * zinv[hd];
  }
  __syncthreads();
  for (int i = tid; i < 4096; i += 256) {
    int hd = qr * 32 + (i >> 7);
    int o = i & 127, h = hd >> 5;
    float a = 0.f;
#pragma unroll
    for (int e = 0; e < 32; e++) a += wout[o * 128 + h * 32 + e] * C[(i >> 7) * 32 + e];
    int f = (o >> 4) * 4 + (hd >> 5);
    int lane = (o & 15) + (((hd >> 3) & 3) << 4);
    Mtf[(size_t)b * 16384 + f * 512 + lane * 8 + (hd & 7)] = f2bf(a);
  }
}

// ---------------- K3: out = Mtf x q + b_out (MFMA) ----------------
__global__ __launch_bounds__(256) void k3_out(
    const unsigned short* __restrict__ qbf, const unsigned short* __restrict__ Mtf,
    const float* __restrict__ bout, float* __restrict__ out) {
  __shared__ __align__(16) unsigned short qf[16 * 512];
  const int b = blockIdx.x >> 6, tile = blockIdx.x & 63;
  const int tid = threadIdx.x;
  const int l = tid & 63, quad = l >> 4, l16 = l & 15;
  const int chunk = __builtin_amdgcn_readfirstlane(tid >> 6);
  const short8* qv = (const short8*)qbf;
  const int base = ((b * 64 + tile) * 16) * 64;  // short8 units
#pragma unroll
  for (int r = 0; r < 4; r++) {
    int cid = tid + 256 * r;
    *(short8*)&qf[cid * 8] = qv[base + cid];
  }
  __syncthreads();
  f32x4 acc[2][4] = {};
  const short8* Mv = (const short8*)Mtf;
#pragma unroll
  for (int k0 = 0; k0 < 4; k0++) {
    short8 bfr[4];
#pragma unroll
    for (int n0 = 0; n0 < 4; n0++)
      bfr[n0] = *(const short8*)&qf[(k0 * 4 + n0) * 512 + l * 8];
#pragma unroll
    for (int mm = 0; mm < 2; mm++) {
      short8 afr = Mv[((size_t)b * 32 + (chunk * 2 + mm) * 4 + k0) * 64 + l];
#pragma unroll
      for (int n0 = 0; n0 < 4; n0++)
        acc[mm][n0] = __builtin_amdgcn_mfma_f32_16x16x32_bf16(afr, bfr[n0], acc[mm][n0], 0, 0, 0);
    }
  }
  float bv[2][4];
#pragma unroll
  for (int mm = 0; mm < 2; mm++)
#pragma unroll
    for (int r = 0; r < 4; r++) bv[mm][r] = bout[chunk * 32 + mm * 16 + quad * 4 + r];
#pragma unroll
  for (int mm = 0; mm < 2; mm++)
#pragma unroll
    for (int n0 = 0; n0 < 4; n0++)
#pragma unroll
      for (int r = 0; r < 4; r++) {
        int o = chunk * 32 + mm * 16 + quad * 4 + r;
        int Pp = tile * 64 + n0 * 16 + l16;
        out[((size_t)b * 128 + o) * 4096 + Pp] = acc[mm][n0][r] + bv[mm][r];
      }
}

extern "C" void kernel_launch(void* const* d_in, const int* in_sizes, int n_in,
                              void* d_out, int out_size, void* d_ws, size_t ws_size,
                              hipStream_t stream) {
  const float* x     = (const float*)d_in[0];
  const float* g     = (const float*)d_in[1];
  const float* wqkv  = (const float*)d_in[2];
  const float* memkv = (const float*)d_in[3];
  const float* wout  = (const float*)d_in[4];
  const float* bout  = (const float*)d_in[5];
  float* out = (float*)d_out;
  float* ws = (float*)d_ws;
  float* Sp  = ws;
  float* Zp  = ws + 2097152;
  unsigned short* Mtf = (unsigned short*)(ws + 2162688);
  unsigned short* Wf  = (unsigned short*)(ws + 2424832);
  float* gs  = ws + 2449408;
  unsigned short* qbf = (unsigned short*)(ws + 2449536);

  k0_init<<<128, 256, 0, stream>>>(wqkv, g, ws);
  k1_qkv<<<512, 256, 0, stream>>>(x, Wf, gs, Sp, Zp, qbf);
  k2_ctx<<<128, 256, 0, stream>>>(Sp, Zp, memkv, wout, Mtf);
  k3_out<<<2048, 256, 0, stream>>>(qbf, Mtf, bout, out);
}

// Round 6
// 196.729 us; speedup vs baseline: 2.7495x; 1.1802x over previous
//
#include <hip/hip_runtime.h>
#include <hip/hip_bf16.h>

typedef __attribute__((ext_vector_type(8))) short short8;   // 8 bf16 (A/B frag)
typedef __attribute__((ext_vector_type(4))) float f32x4;    // 4 fp32 (C/D frag)

// b=32, C=128, n=4096, heads=4, dh=32. All I/O fp32; MFMA bf16, fp32 accum.
// Grid 1024 for K1 (2 sub-tiles/block), bf16 S/Z partials (32 groups).
//
// ws (float units), total 10838144 floats = 41.3 MiB (== round-5 footprint):
//   Sp  bf16 [32][32][4096] @ 0        (2097152 fl-eq)
//   Zp  bf16 [32][32][128]  @ 2097152  (65536 fl-eq... uses 4096 fl)
//   Mtf bf16 frag-major     @ 2162688  (262144 fl)
//   Wf  bf16 frag-major     @ 2424832  (24576 fl)
//   gs  [128]               @ 2449408  (128)
//   qbf bf16 frag-major     @ 2449536  (8388608 fl)

__device__ __forceinline__ unsigned short f2bf(float f) {  // RNE, finite inputs
  unsigned u = __float_as_uint(f);
  u += 0x7fff + ((u >> 16) & 1);
  return (unsigned short)(u >> 16);
}
__device__ __forceinline__ float bf2f(unsigned short s) {
  return __uint_as_float(((unsigned)s) << 16);
}

// ---------------- K0: pack Wf frag-major, gs ----------------
__global__ void k0_init(const float* __restrict__ wqkv, const float* __restrict__ g,
                        float* __restrict__ ws) {
  int tid = blockIdx.x * blockDim.x + threadIdx.x;
  int stride = gridDim.x * blockDim.x;
  unsigned short* Wf = (unsigned short*)(ws + 2424832);
  for (int i = tid; i < 49152; i += stride) {
    int o = i >> 7, c = i & 127;
    int f = (o >> 4) * 4 + (c >> 5);
    int lane = (o & 15) + (((c >> 3) & 3) << 4);
    Wf[f * 512 + lane * 8 + (c & 7)] = f2bf(wqkv[o * 128 + c]);
  }
  float* gs = ws + 2449408;
  if (tid < 128) gs[tid] = g[tid] * 11.313708498984761f;  // sqrt(128)
}

// ---------------- K1: rmsnorm + MFMA qkv + q-softmax + S/Z partials ----------------
// grid 1024 = 32 b * 32 groups; each block does 2 sub-tiles of 64 px.
__global__ __launch_bounds__(256, 4) void k1_qkv(
    const float* __restrict__ x, const unsigned short* __restrict__ Wf,
    const float* __restrict__ gs, unsigned short* __restrict__ Sp,
    unsigned short* __restrict__ Zp, unsigned short* __restrict__ qbf) {
  __shared__ __align__(16) unsigned short xnf[16 * 512];   // B-frags of xn
  __shared__ unsigned short kbuf[128 * 66];                // exp(k) [row][px]
  __shared__ unsigned short vbuf[128 * 66];                // v      [row][px]
  __shared__ float ssred[256];
  const int b = blockIdx.x >> 5, grp = blockIdx.x & 31;
  const int tid = threadIdx.x;
  const int p = tid & 63, w = tid >> 6;
  const int chunk = __builtin_amdgcn_readfirstlane(w);
  const int l = p, quad = l >> 4, l16 = l & 15;

  // phase-4 accumulators persist across sub-tiles
  const int h4 = chunk, d0 = l16, eq = quad;
  float sacc0[8] = {}, sacc1[8] = {};
  float z0 = 0.f, z1 = 0.f;

  for (int t = 0; t < 2; t++) {
    const int tile = grp * 2 + t;
    const int P = tile * 64 + p;
    // phase 1: load x (c = w*32+i), rmsnorm
    const float* xb = x + (size_t)b * 524288 + P;
    float xr[32];
    float ss = 0.f;
#pragma unroll
    for (int i = 0; i < 32; i++) {
      float v = xb[(size_t)(w * 32 + i) * 4096];
      xr[i] = v; ss += v * v;
    }
    ssred[w * 64 + p] = ss;
    __syncthreads();  // (A) also fences prev iter's kbuf/vbuf readers
    float tot = ssred[p] + ssred[64 + p] + ssred[128 + p] + ssred[192 + p];
    float inv = 1.0f / fmaxf(sqrtf(tot), 1e-12f);
#pragma unroll
    for (int q8 = 0; q8 < 4; q8++) {
      short8 v8;
#pragma unroll
      for (int j = 0; j < 8; j++) {
        int i = q8 * 8 + j;
        v8[j] = (short)f2bf(xr[i] * gs[w * 32 + i] * inv);
      }
      *(short8*)&xnf[(w * 4 + (p >> 4)) * 512 + ((p & 15) + q8 * 16) * 8] = v8;
    }
    __syncthreads();  // (B) xnf ready

    // phase 2+3: per-32-row chunk MFMA then immediate epilogue (acc = 32 regs)
    const short8* Wfv = (const short8*)Wf;
#pragma unroll
    for (int s = 0; s < 3; s++) {
      f32x4 acc[2][4] = {};
#pragma unroll
      for (int k0 = 0; k0 < 4; k0++) {
        short8 bfr[4];
#pragma unroll
        for (int n0 = 0; n0 < 4; n0++)
          bfr[n0] = *(const short8*)&xnf[(k0 * 4 + n0) * 512 + l * 8];
#pragma unroll
        for (int off = 0; off < 2; off++) {
          short8 afr = Wfv[((chunk * 6 + 2 * s + off) * 4 + k0) * 64 + l];
#pragma unroll
          for (int n0 = 0; n0 < 4; n0++)
            acc[off][n0] = __builtin_amdgcn_mfma_f32_16x16x32_bf16(afr, bfr[n0], acc[off][n0], 0, 0, 0);
        }
      }
      const int o0 = chunk * 96 + 32 * s;
      if (o0 < 128) {  // q head: per-pixel softmax over d, direct global store
        int h = o0 >> 5;
#pragma unroll
        for (int n0 = 0; n0 < 4; n0++) {
          float m = -1e30f;
#pragma unroll
          for (int off = 0; off < 2; off++)
#pragma unroll
            for (int r = 0; r < 4; r++) m = fmaxf(m, acc[off][n0][r]);
          m = fmaxf(m, __shfl_xor(m, 16, 64));
          m = fmaxf(m, __shfl_xor(m, 32, 64));
          float e[2][4]; float sum = 0.f;
#pragma unroll
          for (int off = 0; off < 2; off++)
#pragma unroll
            for (int r = 0; r < 4; r++) {
              e[off][r] = __expf(acc[off][n0][r] - m);
              sum += e[off][r];
            }
          sum += __shfl_xor(sum, 16, 64);
          sum += __shfl_xor(sum, 32, 64);
          float rs = 0.17677669529663687f / sum;  // dh^-0.5 / sum
          int qbase = ((b * 64 + tile) * 16 + h * 4 + n0) * 512;
#pragma unroll
          for (int off = 0; off < 2; off++)
#pragma unroll
            for (int r = 0; r < 4; r++) {
              int lane2 = l16 + ((off * 2 + (quad >> 1)) << 4);
              int jj = (quad & 1) * 4 + r;
              qbf[qbase + lane2 * 8 + jj] = f2bf(e[off][r] * rs);
            }
        }
      } else if (o0 < 256) {  // k head -> exp -> LDS
        int h = (o0 - 128) >> 5;
#pragma unroll
        for (int n0 = 0; n0 < 4; n0++)
#pragma unroll
          for (int off = 0; off < 2; off++)
#pragma unroll
            for (int r = 0; r < 4; r++) {
              int row = h * 32 + off * 16 + quad * 4 + r;
              kbuf[row * 66 + n0 * 16 + l16] = f2bf(__expf(acc[off][n0][r]));
            }
      } else {  // v head
        int h = (o0 - 256) >> 5;
#pragma unroll
        for (int n0 = 0; n0 < 4; n0++)
#pragma unroll
          for (int off = 0; off < 2; off++)
#pragma unroll
            for (int r = 0; r < 4; r++) {
              int row = h * 32 + off * 16 + quad * 4 + r;
              vbuf[row * 66 + n0 * 16 + l16] = f2bf(acc[off][n0][r]);
            }
      }
    }
    __syncthreads();  // (C) kbuf/vbuf ready

    // phase 4: accumulate S/Z for this sub-tile. wave = head.
    const unsigned short* kr0 = kbuf + (h4 * 32 + d0) * 66;
    const unsigned short* kr1 = kr0 + 16 * 66;
    const unsigned short* vr = vbuf + (h4 * 32 + 8 * eq) * 66;
#pragma unroll 4
    for (int pp = 0; pp < 32; pp++) {  // 2 px/iter (packed bf16 pair)
      unsigned ka = *(const unsigned*)&kr0[2 * pp];
      unsigned kc = *(const unsigned*)&kr1[2 * pp];
      float k0e = __uint_as_float(ka << 16), k0o = __uint_as_float(ka & 0xffff0000u);
      float k1e = __uint_as_float(kc << 16), k1o = __uint_as_float(kc & 0xffff0000u);
      z0 += k0e + k0o; z1 += k1e + k1o;
#pragma unroll
      for (int j = 0; j < 8; j++) {
        unsigned vv = *(const unsigned*)&vr[j * 66 + 2 * pp];
        float ve = __uint_as_float(vv << 16), vo = __uint_as_float(vv & 0xffff0000u);
        sacc0[j] += k0e * ve + k0o * vo;
        sacc1[j] += k1e * ve + k1o * vo;
      }
    }
  }

  // write bf16 partials (coalesced 16 B stores, no atomics)
  unsigned short* Spb = Sp + (size_t)(b * 32 + grp) * 4096;
  short8 s0, s1;
#pragma unroll
  for (int j = 0; j < 8; j++) { s0[j] = (short)f2bf(sacc0[j]); s1[j] = (short)f2bf(sacc1[j]); }
  *(short8*)&Spb[(h4 * 32 + d0) * 32 + 8 * eq] = s0;
  *(short8*)&Spb[(h4 * 32 + d0 + 16) * 32 + 8 * eq] = s1;
  if (eq == 0) {
    Zp[(b * 32 + grp) * 128 + h4 * 32 + d0] = f2bf(z0);
    Zp[(b * 32 + grp) * 128 + h4 * 32 + d0 + 16] = f2bf(z1);
  }
}

// ---------------- K2: reduce partials + context + fold w_out -> Mtf ----------------
__global__ void k2_ctx(const unsigned short* __restrict__ Sp, const unsigned short* __restrict__ Zp,
                       const float* __restrict__ memkv, const float* __restrict__ wout,
                       unsigned short* __restrict__ Mtf) {
  __shared__ float C[1024];    // this quarter's rows [32][32]
  __shared__ float zinv[128];
  const int b = blockIdx.x >> 2, qr = blockIdx.x & 3, tid = threadIdx.x;
  if (tid < 128) {
    float z = 0.f;
#pragma unroll
    for (int g = 0; g < 32; g++) z += bf2f(Zp[(b * 32 + g) * 128 + tid]);
    float zm = 0.f;
#pragma unroll
    for (int j = 0; j < 4; j++) zm += __expf(memkv[tid * 4 + j]);
    zinv[tid] = 1.0f / (z + zm);
  }
  __syncthreads();
  for (int i = tid; i < 1024; i += 256) {
    int idx = qr * 1024 + i;
    int hd = idx >> 5, e = idx & 31, h = hd >> 5;
    float s = 0.f;
#pragma unroll
    for (int g = 0; g < 32; g++) s += bf2f(Sp[(size_t)(b * 32 + g) * 4096 + idx]);
    float sm = 0.f;
#pragma unroll
    for (int j = 0; j < 4; j++)
      sm += __expf(memkv[hd * 4 + j]) * memkv[512 + (h * 32 + e) * 4 + j];
    C[i] = (s + sm) * zinv[hd];
  }
  __syncthreads();
  for (int i = tid; i < 4096; i += 256) {
    int hd = qr * 32 + (i >> 7);
    int o = i & 127, h = hd >> 5;
    float a = 0.f;
#pragma unroll
    for (int e = 0; e < 32; e++) a += wout[o * 128 + h * 32 + e] * C[(i >> 7) * 32 + e];
    int f = (o >> 4) * 4 + (hd >> 5);
    int lane = (o & 15) + (((hd >> 3) & 3) << 4);
    Mtf[(size_t)b * 16384 + f * 512 + lane * 8 + (hd & 7)] = f2bf(a);
  }
}

// ---------------- K3: out = Mtf x q + b_out (MFMA, LDS-restaged stores) ----------------
__global__ __launch_bounds__(256) void k3_out(
    const unsigned short* __restrict__ qbf, const unsigned short* __restrict__ Mtf,
    const float* __restrict__ bout, float* __restrict__ out) {
  __shared__ __align__(16) unsigned short qf[16 * 512];
  __shared__ __align__(16) float obuf[128 * 68];
  const int b = blockIdx.x >> 6, tile = blockIdx.x & 63;
  const int tid = threadIdx.x;
  const int l = tid & 63, quad = l >> 4, l16 = l & 15;
  const int chunk = __builtin_amdgcn_readfirstlane(tid >> 6);
  const short8* qv = (const short8*)qbf;
  const int base = ((b * 64 + tile) * 16) * 64;  // short8 units
#pragma unroll
  for (int r = 0; r < 4; r++) {
    int cid = tid + 256 * r;
    *(short8*)&qf[cid * 8] = qv[base + cid];
  }
  __syncthreads();
  f32x4 acc[2][4] = {};
  const short8* Mv = (const short8*)Mtf;
#pragma unroll
  for (int k0 = 0; k0 < 4; k0++) {
    short8 bfr[4];
#pragma unroll
    for (int n0 = 0; n0 < 4; n0++)
      bfr[n0] = *(const short8*)&qf[(k0 * 4 + n0) * 512 + l * 8];
#pragma unroll
    for (int mm = 0; mm < 2; mm++) {
      short8 afr = Mv[((size_t)b * 32 + (chunk * 2 + mm) * 4 + k0) * 64 + l];
#pragma unroll
      for (int n0 = 0; n0 < 4; n0++)
        acc[mm][n0] = __builtin_amdgcn_mfma_f32_16x16x32_bf16(afr, bfr[n0], acc[mm][n0], 0, 0, 0);
    }
  }
#pragma unroll
  for (int mm = 0; mm < 2; mm++)
#pragma unroll
    for (int r = 0; r < 4; r++) {
      float bv = bout[chunk * 32 + mm * 16 + quad * 4 + r];
#pragma unroll
      for (int n0 = 0; n0 < 4; n0++) {
        int o = chunk * 32 + mm * 16 + quad * 4 + r;
        obuf[o * 68 + n0 * 16 + l16] = acc[mm][n0][r] + bv;
      }
    }
  __syncthreads();
#pragma unroll
  for (int rr = 0; rr < 8; rr++) {
    int idx = tid + 256 * rr;     // 0..2047 = 128 rows * 16 float4
    int row = idx >> 4, c4 = idx & 15;
    f32x4 v = *(const f32x4*)&obuf[row * 68 + c4 * 4];
    *(f32x4*)&out[((size_t)b * 128 + row) * 4096 + tile * 64 + c4 * 4] = v;
  }
}

extern "C" void kernel_launch(void* const* d_in, const int* in_sizes, int n_in,
                              void* d_out, int out_size, void* d_ws, size_t ws_size,
                              hipStream_t stream) {
  const float* x     = (const float*)d_in[0];
  const float* g     = (const float*)d_in[1];
  const float* wqkv  = (const float*)d_in[2];
  const float* memkv = (const float*)d_in[3];
  const float* wout  = (const float*)d_in[4];
  const float* bout  = (const float*)d_in[5];
  float* out = (float*)d_out;
  float* ws = (float*)d_ws;
  unsigned short* Sp  = (unsigned short*)ws;
  unsigned short* Zp  = (unsigned short*)(ws + 2097152);
  unsigned short* Mtf = (unsigned short*)(ws + 2162688);
  unsigned short* Wf  = (unsigned short*)(ws + 2424832);
  float* gs  = ws + 2449408;
  unsigned short* qbf = (unsigned short*)(ws + 2449536);

  k0_init<<<128, 256, 0, stream>>>(wqkv, g, ws);
  k1_qkv<<<1024, 256, 0, stream>>>(x, Wf, gs, Sp, Zp, qbf);
  k2_ctx<<<128, 256, 0, stream>>>(Sp, Zp, memkv, wout, Mtf);
  k3_out<<<2048, 256, 0, stream>>>(qbf, Mtf, bout, out);
}